// Round 5
// baseline (93.568 us; speedup 1.0000x reference)
//
#include <hip/hip_runtime.h>
#include <hip/hip_bf16.h>

#define EPSW 1e-6f

typedef __attribute__((ext_vector_type(4))) float floatx4;
typedef __attribute__((ext_vector_type(4))) unsigned int uintx4;
typedef __attribute__((ext_vector_type(8))) short shortx8;   // 8 bf16 (4 VGPRs)

// round-to-nearest-even float -> bf16 bits (finite inputs)
__device__ __forceinline__ unsigned short f2bf(float f) {
    unsigned int u = __float_as_uint(f);
    u = (u + 0x7fffu + ((u >> 16) & 1u)) >> 16;
    return (unsigned short)u;
}

__device__ __forceinline__ unsigned int pk2(float lo, float hi) {
    return (unsigned int)f2bf(lo) | ((unsigned int)f2bf(hi) << 16);
}

__device__ __forceinline__ uintx4 pk8(floatx4 a, floatx4 b) {
    uintx4 r;
    r.x = pk2(a.x, a.y); r.y = pk2(a.z, a.w);
    r.z = pk2(b.x, b.y); r.w = pk2(b.z, b.w);
    return r;
}

// ---------------------------------------------------------------------------
// gemm_mt: 516 blocks x 256 threads (4 waves) -- 2 independent blocks/CU.
//   blocks 0..511  : GEMM tile. ks = bid&7 (K-slice of 256; &7 so the
//                    round-robin XCD assignment clusters each W k-slice in
//                    one XCD L2), bb2 = bid>>3 (32-row tile: rows bb2*32..+31).
//   blocks 512..515: Mt[c][n] = (A@A)[n][c], 16 n-rows per block.
// A (x) and B (W) reg-staged fp32 with fused bf16 convert into
// double-buffered LDS granule layout; 4 chunks of BK=64; 2-DEEP register
// prefetch (chunk c+2 loads issue while chunk c computes); ONE barrier per
// chunk (buffer reuse is transitively ordered by the next chunk's barrier).
// LDS/buf: A 8kg x 32row x 16B = 4 KB | B 8kg x 128h x 16B = 16 KB -> 40 KB.
// Compute: wave w owns h-tiles {w, w+4}; acc[2 row-tiles][2] = 8 MFMA/chunk.
// Epilogue: fp32 partials to zp[ks][row][h] (unique owner, plain stores).
// ---------------------------------------------------------------------------
__global__ __launch_bounds__(256) void gemm_mt(
        const float* __restrict__ x,
        const float* __restrict__ W,
        const int* __restrict__ ei,
        const float* __restrict__ ew,
        float* __restrict__ zp,
        float* __restrict__ Mt) {
    __shared__ __align__(16) unsigned char smem[2][20480];  // 40 KB
    const int bid = blockIdx.x;
    const int t   = threadIdx.x;

    if (bid >= 512) {
        // ---- Mt = (A@A)^T build, n-slice [bm*16, bm*16+16), 256 thr -------
        const int bm = bid - 512;
        float* A    = (float*)smem;            // 4096 f, A[n][k]
        float* deg  = A + 4096;
        float* dinv = deg + 64;
        if (t < 64) deg[t] = 1.0f;             // self-loop pre-added
        for (int i = t; i < 4096; i += 256) A[i] = 0.0f;
        __syncthreads();
        const int* srcp = ei;
        const int* dstp = ei + 4096;
#pragma unroll
        for (int i = 0; i < 16; ++i) {
            const int e = i * 256 + t;
            float w = ew[e];
            w = (w <= 0.0f) ? EPSW : w;
            atomicAdd(&deg[dstp[e]], w);
        }
        __syncthreads();
        if (t < 64) dinv[t] = 1.0f / sqrtf(deg[t]);
        __syncthreads();
#pragma unroll
        for (int i = 0; i < 16; ++i) {
            const int e = i * 256 + t;
            float w = ew[e];
            w = (w <= 0.0f) ? EPSW : w;
            const int s = srcp[e], d = dstp[e];
            atomicAdd(&A[d * 64 + s], dinv[s] * w * dinv[d]);
        }
        if (t < 64) atomicAdd(&A[t * 64 + t], dinv[t] * dinv[t]);
        __syncthreads();
        const int c  = t & 63;
        const int rr = t >> 6;                 // 0..3 (wave-uniform)
        float s0 = 0.f, s1 = 0.f, s2 = 0.f, s3 = 0.f;
#pragma unroll 8
        for (int k = 0; k < 64; ++k) {
            const float akc = A[k * 64 + c];
            const float* an = A + (bm * 16 + rr * 4) * 64 + k;
            s0 += an[0]   * akc;
            s1 += an[64]  * akc;
            s2 += an[128] * akc;
            s3 += an[192] * akc;
        }
        float* mo = Mt + c * 64 + bm * 16 + rr * 4;
        mo[0] = s0; mo[1] = s1; mo[2] = s2; mo[3] = s3;
        return;
    }

    // ---- GEMM blocks ------------------------------------------------------
    const int ks    = bid & 7;          // K-slice (XCD-clustered)
    const int bb2   = bid >> 3;         // 0..63: 32-row tile
    const int rbase = bb2 * 32;
    const int kbase = ks * 256;

    const int wave = t >> 6, lane = t & 63;
    const int m = lane & 15, q = lane >> 4;
    const int kq = t & 7;               // staging granule col 0..7
    const int rw = t >> 3;              // staging row 0..31

    floatx4 acc[2][2];
#pragma unroll
    for (int rt = 0; rt < 2; ++rt)
#pragma unroll
        for (int hh = 0; hh < 2; ++hh)
            acc[rt][hh] = (floatx4){0.f, 0.f, 0.f, 0.f};

    // 2-deep staging register sets (all indices compile-time: loops unrolled)
    floatx4 rA[2][2];    // [set][half]           : x row, 32 B
    floatx4 rB[2][8];    // [set][row j*2 + half] : W rows rw+32j, 32 B each

#define LOADC(c)                                                              \
    {                                                                         \
        const int s_ = (c) & 1;                                               \
        const int k_ = kbase + (c) * 64 + kq * 8;                             \
        if (k_ < 2000) {                                                      \
            const float* pa_ = x + (size_t)(rbase + rw) * 2000 + k_;          \
            rA[s_][0] = *(const floatx4*)pa_;                                 \
            rA[s_][1] = *(const floatx4*)(pa_ + 4);                           \
            _Pragma("unroll")                                                 \
            for (int j_ = 0; j_ < 4; ++j_) {                                  \
                const float* pw_ = W + (size_t)(rw + 32 * j_) * 2000 + k_;    \
                rB[s_][j_ * 2]     = *(const floatx4*)pw_;                    \
                rB[s_][j_ * 2 + 1] = *(const floatx4*)(pw_ + 4);              \
            }                                                                 \
        } else {                                                              \
            rA[s_][0] = rA[s_][1] = (floatx4){0.f, 0.f, 0.f, 0.f};            \
            _Pragma("unroll")                                                 \
            for (int j_ = 0; j_ < 8; ++j_)                                    \
                rB[s_][j_] = (floatx4){0.f, 0.f, 0.f, 0.f};                   \
        }                                                                     \
    }

#define WRITEC(c)                                                             \
    {                                                                         \
        const int s_ = (c) & 1;                                               \
        unsigned char* sb_ = smem[s_];                                        \
        *(uintx4*)(sb_ + kq * 512 + rw * 16) = pk8(rA[s_][0], rA[s_][1]);     \
        _Pragma("unroll")                                                     \
        for (int j_ = 0; j_ < 4; ++j_)                                        \
            *(uintx4*)(sb_ + 4096 + kq * 2048 + (rw + 32 * j_) * 16) =        \
                pk8(rB[s_][j_ * 2], rB[s_][j_ * 2 + 1]);                      \
    }

    LOADC(0);
    LOADC(1);
#pragma unroll
    for (int c = 0; c < 4; ++c) {
        WRITEC(c);                       // waits (fine-grained) on set c&1
        if (c < 2) LOADC(c + 2);         // keep 2 chunks in flight
        __syncthreads();                 // staging of buf c&1 published;
                                         // also orders reuse (chunk c-2 done)
        const unsigned char* sb = smem[c & 1];
#pragma unroll
        for (int p = 0; p < 2; ++p) {
            const int kgq = p * 4 + q;
            shortx8 af[2];
#pragma unroll
            for (int rt = 0; rt < 2; ++rt)
                af[rt] = *(const shortx8*)(sb + kgq * 512 + (rt * 16 + m) * 16);
            shortx8 bf[2];
#pragma unroll
            for (int hh = 0; hh < 2; ++hh)
                bf[hh] = *(const shortx8*)(sb + 4096 + kgq * 2048 +
                                           ((wave + hh * 4) * 16 + m) * 16);
#pragma unroll
            for (int rt = 0; rt < 2; ++rt)
#pragma unroll
                for (int hh = 0; hh < 2; ++hh)
                    acc[rt][hh] = __builtin_amdgcn_mfma_f32_16x16x32_bf16(
                        af[rt], bf[hh], acc[rt][hh], 0, 0, 0);
        }
    }
#undef LOADC
#undef WRITEC

    // epilogue: partial z. C/D layout: row = q*4+v, col = m.
    float* zslice = zp + ((size_t)ks * 2048 + rbase) * 128;
#pragma unroll
    for (int rt = 0; rt < 2; ++rt)
#pragma unroll
        for (int hh = 0; hh < 2; ++hh) {
            const int h = (wave + hh * 4) * 16 + m;
#pragma unroll
            for (int v = 0; v < 4; ++v) {
                const int n = rt * 16 + q * 4 + v;
                zslice[n * 128 + h] = acc[rt][hh][v];
            }
        }
}

// ---------------------------------------------------------------------------
// apply_M: y[b][n][h] = bias[h] + sum_m M[n][m] * (sum_ks zp[ks][b*64+m][h])
// Grid (32 b, 8 h-chunks of 16) x 256 thr (r1-proven).
// ---------------------------------------------------------------------------
__global__ __launch_bounds__(256) void apply_M(const float* __restrict__ zp,
                                               const float* __restrict__ Mtg,
                                               const float* __restrict__ bias,
                                               float* __restrict__ y) {
    __shared__ float Ms[4096];
    __shared__ float zs[64][16];
    const int b  = blockIdx.x;
    const int hc = blockIdx.y;
    const int t  = threadIdx.x;
#pragma unroll
    for (int i = 0; i < 16; ++i) Ms[i * 256 + t] = Mtg[i * 256 + t];
#pragma unroll
    for (int i = 0; i < 4; ++i) {
        const int idx = i * 256 + t;
        const int mr = idx >> 4, hh = idx & 15;
        float s = 0.0f;
#pragma unroll
        for (int ks = 0; ks < 8; ++ks)
            s += zp[((size_t)ks * 2048 + b * 64 + mr) * 128 + hc * 16 + hh];
        zs[mr][hh] = s;
    }
    __syncthreads();
    const int h  = t & 15;
    const int n0 = (t >> 4) * 4;
    const float bv = bias[hc * 16 + h];
    float s0 = bv, s1 = bv, s2 = bv, s3 = bv;
#pragma unroll
    for (int mm = 0; mm < 64; ++mm) {
        const float zv = zs[mm][h];
        s0 += Ms[mm * 64 + n0 + 0] * zv;
        s1 += Ms[mm * 64 + n0 + 1] * zv;
        s2 += Ms[mm * 64 + n0 + 2] * zv;
        s3 += Ms[mm * 64 + n0 + 3] * zv;
    }
    float* yp = y + (size_t)b * 8192 + (size_t)n0 * 128 + hc * 16 + h;
    yp[0]   = s0;
    yp[128] = s1;
    yp[256] = s2;
    yp[384] = s3;
}

extern "C" void kernel_launch(void* const* d_in, const int* in_sizes, int n_in,
                              void* d_out, int out_size, void* d_ws, size_t ws_size,
                              hipStream_t stream) {
    const float* x    = (const float*)d_in[0];   // (2048, 2000) fp32 (flat view)
    const int*   ei   = (const int*)d_in[1];     // (2, 4096)
    const float* ew   = (const float*)d_in[2];   // (4096,)
    const float* W    = (const float*)d_in[3];   // (128, 2000) fp32
    const float* bias = (const float*)d_in[4];   // (128,)
    float* y = (float*)d_out;                    // (32, 64, 128) fp32

    float* zp = (float*)d_ws;                    // 8*2048*128 f (8 MB)
    float* Mt = zp + 2097152;                    // 4096 f

    gemm_mt<<<516, 256, 0, stream>>>(x, W, ei, ew, zp, Mt);
    apply_M<<<dim3(32, 8), 256, 0, stream>>>(zp, Mt, bias, y);
}

// Round 6
// 89.255 us; speedup vs baseline: 1.0483x; 1.0483x over previous
//
#include <hip/hip_runtime.h>
#include <hip/hip_bf16.h>

#define EPSW 1e-6f

typedef __attribute__((ext_vector_type(4))) float floatx4;
typedef __attribute__((ext_vector_type(4))) unsigned int uintx4;
typedef __attribute__((ext_vector_type(8))) short shortx8;   // 8 bf16 (4 VGPRs)

// round-to-nearest-even float -> bf16 bits (finite inputs)
__device__ __forceinline__ unsigned short f2bf(float f) {
    unsigned int u = __float_as_uint(f);
    u = (u + 0x7fffu + ((u >> 16) & 1u)) >> 16;
    return (unsigned short)u;
}

__device__ __forceinline__ unsigned int pk2(float lo, float hi) {
    return (unsigned int)f2bf(lo) | ((unsigned int)f2bf(hi) << 16);
}

__device__ __forceinline__ uintx4 pk8(floatx4 a, floatx4 b) {
    uintx4 r;
    r.x = pk2(a.x, a.y); r.y = pk2(a.z, a.w);
    r.z = pk2(b.x, b.y); r.w = pk2(b.z, b.w);
    return r;
}

// ---------------------------------------------------------------------------
// gemm_mt: 260 blocks x 512 threads (8 waves).
//   blocks 0..255  : GEMM tile. ks = bid&7 (K-slice of 256; same-ks blocks
//                    land on one XCD under round-robin dispatch -> W slice
//                    L2-resident), rt2 = bid>>3 (rows rt2*64..+63).
//   blocks 256..259: Mt[c][n] = (A@A)[n][c], 16 n-rows per block (r4 code).
// W-RESIDENT design: the block's W k-slice (32 kg x 128 h bf16 granules,
// 64 KB) is converted fp32->bf16 and staged into LDS ONCE, then the 4-chunk
// K-loop stages ONLY x: per chunk per thread 32 B global + 8 pack + 1
// ds_write_b128 (vs r4's 96 B + 3 writes incl. W re-stage every chunk).
// 2-deep x register prefetch; ONE barrier per chunk (buffer reuse at c+2 is
// ordered by barrier c+1). LDS: W 64 KB + X 2x8 KB = 80 KB.
// Fragment/addressing math identical to r4 (proven): wave w owns h-tile w
// (h = w*16+m); acc[4 row-tiles]; 8 MFMA/chunk/wave.
// Epilogue: fp32 partials to zp[ks][row][h] (unique owner, plain stores).
// ---------------------------------------------------------------------------
__global__ __launch_bounds__(512) void gemm_mt(
        const float* __restrict__ x,
        const float* __restrict__ W,
        const int* __restrict__ ei,
        const float* __restrict__ ew,
        float* __restrict__ zp,
        float* __restrict__ Mt) {
    __shared__ __align__(16) unsigned char smem[81920];  // 64K W + 2x8K X
    const int bid = blockIdx.x;
    const int t   = threadIdx.x;

    if (bid >= 256) {
        // ---- Mt = (A@A)^T build, n-slice [bm*16, bm*16+16) (r4-proven) ----
        const int bm = bid - 256;
        float* A    = (float*)smem;            // 4096 f, A[n][k]
        float* deg  = A + 4096;
        float* dinv = deg + 64;
        if (t < 64) deg[t] = 1.0f;             // self-loop pre-added
        for (int i = t; i < 4096; i += 512) A[i] = 0.0f;
        __syncthreads();
        const int* srcp = ei;
        const int* dstp = ei + 4096;
#pragma unroll
        for (int i = 0; i < 8; ++i) {
            const int e = i * 512 + t;
            float w = ew[e];
            w = (w <= 0.0f) ? EPSW : w;
            atomicAdd(&deg[dstp[e]], w);
        }
        __syncthreads();
        if (t < 64) dinv[t] = 1.0f / sqrtf(deg[t]);
        __syncthreads();
#pragma unroll
        for (int i = 0; i < 8; ++i) {
            const int e = i * 512 + t;
            float w = ew[e];
            w = (w <= 0.0f) ? EPSW : w;
            const int s = srcp[e], d = dstp[e];
            atomicAdd(&A[d * 64 + s], dinv[s] * w * dinv[d]);
        }
        if (t < 64) atomicAdd(&A[t * 64 + t], dinv[t] * dinv[t]);
        __syncthreads();
        const int c  = t & 63;
        const int n0 = bm * 16 + (t >> 6);
        const int n1 = n0 + 8;
        float s0 = 0.0f, s1 = 0.0f;
#pragma unroll 8
        for (int k = 0; k < 64; ++k) {
            const float akc = A[k * 64 + c];
            s0 += A[n0 * 64 + k] * akc;
            s1 += A[n1 * 64 + k] * akc;
        }
        Mt[c * 64 + n0] = s0;
        Mt[c * 64 + n1] = s1;
        return;
    }

    // ---- GEMM blocks ------------------------------------------------------
    const int ks    = bid & 7;          // K-slice (XCD-clustered)
    const int rt2   = bid >> 3;         // 0..31
    const int rbase = rt2 * 64;
    const int kbase = ks * 256;

    unsigned char* Wl = smem;           // [32 kg][128 h] granules, 64 KB
    unsigned char* Xl = smem + 65536;   // [2 buf][8 kg][64 row], 2x8 KB

    // ---- stage W k-slice once: 4096 granules / 512 thr = 8 per thread ----
#pragma unroll
    for (int i = 0; i < 8; ++i) {
        const int G  = i * 512 + t;
        const int kg = G >> 7, h = G & 127;
        const int k  = kbase + kg * 8;
        floatx4 v0 = (floatx4){0.f, 0.f, 0.f, 0.f};
        floatx4 v1 = (floatx4){0.f, 0.f, 0.f, 0.f};
        if (k < 2000) {
            v0 = *(const floatx4*)(W + (size_t)h * 2000 + k);
            v1 = *(const floatx4*)(W + (size_t)h * 2000 + k + 4);
        }
        *(uintx4*)(Wl + ((size_t)(kg * 128 + h)) * 16) = pk8(v0, v1);
    }
    // (first chunk's barrier publishes Wl before any B-read)

    const int wave = t >> 6, lane = t & 63;
    const int m = lane & 15, q = lane >> 4;
    const int kq = t & 7;               // x staging granule col 0..7
    const int rw = t >> 3;              // x staging row 0..63

    floatx4 acc[4];
#pragma unroll
    for (int rt = 0; rt < 4; ++rt) acc[rt] = (floatx4){0.f, 0.f, 0.f, 0.f};

    floatx4 rX[2][2];   // 2-deep staging sets (compile-time indexed)

#define LOADX(c)                                                              \
    {                                                                         \
        const int s_ = (c) & 1;                                               \
        const int k_ = kbase + (c) * 64 + kq * 8;                             \
        if (k_ < 2000) {                                                      \
            const float* p_ = x + (size_t)(rbase + rw) * 2000 + k_;           \
            rX[s_][0] = *(const floatx4*)p_;                                  \
            rX[s_][1] = *(const floatx4*)(p_ + 4);                            \
        } else {                                                              \
            rX[s_][0] = rX[s_][1] = (floatx4){0.f, 0.f, 0.f, 0.f};            \
        }                                                                     \
    }

#define WRITEX(c)                                                             \
    {                                                                         \
        const int s_ = (c) & 1;                                               \
        *(uintx4*)(Xl + s_ * 8192 + (kq * 64 + rw) * 16) =                    \
            pk8(rX[s_][0], rX[s_][1]);                                        \
    }

    LOADX(0);
    LOADX(1);
#pragma unroll
    for (int c = 0; c < 4; ++c) {
        WRITEX(c);                       // fine-grained vmcnt on set c&1
        if (c < 2) LOADX(c + 2);         // keep 2 chunks in flight
        __syncthreads();                 // publishes X buf c&1 (and Wl at c=0);
                                         // orders reuse of buf at c+2
        const unsigned char* sx = Xl + (c & 1) * 8192;
#pragma unroll
        for (int p = 0; p < 2; ++p) {
            const int kgq = p * 4 + q;
            shortx8 af[4];
#pragma unroll
            for (int rt = 0; rt < 4; ++rt)
                af[rt] = *(const shortx8*)(sx + (kgq * 64 + rt * 16 + m) * 16);
            const shortx8 bf = *(const shortx8*)(
                Wl + (((c * 8 + kgq) * 128) + wave * 16 + m) * 16);
#pragma unroll
            for (int rt = 0; rt < 4; ++rt)
                acc[rt] = __builtin_amdgcn_mfma_f32_16x16x32_bf16(
                    af[rt], bf, acc[rt], 0, 0, 0);
        }
    }
#undef LOADX
#undef WRITEX

    // epilogue: partial z. C/D layout: row = q*4+v, col = m.
    float* zslice = zp + ((size_t)ks * 2048 + rbase) * 128;
    const int h = wave * 16 + m;
#pragma unroll
    for (int rt = 0; rt < 4; ++rt) {
#pragma unroll
        for (int v = 0; v < 4; ++v) {
            const int n = rt * 16 + q * 4 + v;
            zslice[n * 128 + h] = acc[rt][v];
        }
    }
}

// ---------------------------------------------------------------------------
// apply_M: y[b][n][h] = bias[h] + sum_m M[n][m] * (sum_ks zp[ks][b*64+m][h])
// Grid (32 b, 8 h-chunks of 16) x 256 thr (r1-proven).
// ---------------------------------------------------------------------------
__global__ __launch_bounds__(256) void apply_M(const float* __restrict__ zp,
                                               const float* __restrict__ Mtg,
                                               const float* __restrict__ bias,
                                               float* __restrict__ y) {
    __shared__ float Ms[4096];
    __shared__ float zs[64][16];
    const int b  = blockIdx.x;
    const int hc = blockIdx.y;
    const int t  = threadIdx.x;
#pragma unroll
    for (int i = 0; i < 16; ++i) Ms[i * 256 + t] = Mtg[i * 256 + t];
#pragma unroll
    for (int i = 0; i < 4; ++i) {
        const int idx = i * 256 + t;
        const int mr = idx >> 4, hh = idx & 15;
        float s = 0.0f;
#pragma unroll
        for (int ks = 0; ks < 8; ++ks)
            s += zp[((size_t)ks * 2048 + b * 64 + mr) * 128 + hc * 16 + hh];
        zs[mr][hh] = s;
    }
    __syncthreads();
    const int h  = t & 15;
    const int n0 = (t >> 4) * 4;
    const float bv = bias[hc * 16 + h];
    float s0 = bv, s1 = bv, s2 = bv, s3 = bv;
#pragma unroll
    for (int mm = 0; mm < 64; ++mm) {
        const float zv = zs[mm][h];
        s0 += Ms[mm * 64 + n0 + 0] * zv;
        s1 += Ms[mm * 64 + n0 + 1] * zv;
        s2 += Ms[mm * 64 + n0 + 2] * zv;
        s3 += Ms[mm * 64 + n0 + 3] * zv;
    }
    float* yp = y + (size_t)b * 8192 + (size_t)n0 * 128 + hc * 16 + h;
    yp[0]   = s0;
    yp[128] = s1;
    yp[256] = s2;
    yp[384] = s3;
}

extern "C" void kernel_launch(void* const* d_in, const int* in_sizes, int n_in,
                              void* d_out, int out_size, void* d_ws, size_t ws_size,
                              hipStream_t stream) {
    const float* x    = (const float*)d_in[0];   // (2048, 2000) fp32 (flat view)
    const int*   ei   = (const int*)d_in[1];     // (2, 4096)
    const float* ew   = (const float*)d_in[2];   // (4096,)
    const float* W    = (const float*)d_in[3];   // (128, 2000) fp32
    const float* bias = (const float*)d_in[4];   // (128,)
    float* y = (float*)d_out;                    // (32, 64, 128) fp32

    float* zp = (float*)d_ws;                    // 8*2048*128 f (8 MB)
    float* Mt = zp + 2097152;                    // 4096 f

    gemm_mt<<<260, 512, 0, stream>>>(x, W, ei, ew, zp, Mt);
    apply_M<<<dim3(32, 8), 256, 0, stream>>>(zp, Mt, bias, y);
}